// Round 7
// baseline (232.069 us; speedup 1.0000x reference)
//
#include <hip/hip_runtime.h>

// ECNR forward, R22 = R21 + intra-wave MFMA/VALU pairing:
//  R21 post-mortem: MfmaUtil(40%)+VALUBusy(39%) ~= 80% at 122us wall =>
//  pipes run SERIALLY. All 4 resident blocks/CU phase-lock (same start,
//  identical durations), so cross-wave overlap (m114) never happens.
//  R22 makes overlap structural: each block's 64 points = two 32-pt tiles
//  T1/T2 run ONE LAYER OUT OF PHASE in the same waves. Every segment pairs
//  tile X's MFMA loop with tile Y's sin/pack epilogue (independent regs,
//  compiler interleaves VALU into the MFMA dependency bubbles in-wave).
//    Seg0: T1.L0+epi, T2.L0(mfma)        | bar
//    Seg1: T1.L1mfma  ||  T2.L0epi       | bar
//    Seg2: T2.L1mfma  ||  T1.L1epi       | bar   (wl8 W1 panel reused!)
//    Seg3: T1.L2mfma  ||  T2.L1epi       | bar
//    Seg4: T2.L2mfma  ||  T1.L3tail->red
//    Seg5: T2.L3tail->red                | bar | out
//  Register budget: acc 16/tile (single chain) x2 + wl8 32 (shared, same m)
//  + transients ~= 95-105 (R17-proven envelope). LDS 4x[32][128]u16 + red
//  = 33792 B -> 4 blocks/CU. Same MFMA/sin counts, same per-tile FP order:
//  absmax 0.03320312. setprio dropped (overlap now intra-wave).

typedef unsigned int u32;
typedef unsigned short u16;
typedef __bf16 v8bf  __attribute__((ext_vector_type(8)));
typedef __bf16 v2bf  __attribute__((ext_vector_type(2)));
typedef float  v16f  __attribute__((ext_vector_type(16)));
typedef float  v2f   __attribute__((ext_vector_type(2)));
typedef u32    v4u   __attribute__((ext_vector_type(4)));
typedef u32    v2u   __attribute__((ext_vector_type(2)));

#define MFMA(a, b, c) __builtin_amdgcn_mfma_f32_32x32x16_bf16(a, b, c, 0, 0, 0)

#define HSTRIDE 128                 // u16; 256 B rows, XOR-swizzled chunks
#define OMEGA_S 4.774648292756860f  // 30/(2*pi)

__device__ __forceinline__ float sinrev(float rev) {
    return __builtin_amdgcn_sinf(__builtin_amdgcn_fractf(rev));
}

__device__ __forceinline__ u32 pack2(float c) {
    __bf16 b0 = (__bf16)c;
    float  f0 = (float)b0;
    __bf16 b1 = (__bf16)(c - f0);
    return (u32)__builtin_bit_cast(u16, b0) |
           ((u32)__builtin_bit_cast(u16, b1) << 16);
}

// two floats -> packed lo (bf16x2) and packed hi (residual bf16x2), RNE
__device__ __forceinline__ void pk2(float s0, float s1, u32& lo, u32& hi) {
    v2f s; s[0] = s0; s[1] = s1;
    v2bf l = __builtin_convertvector(s, v2bf);        // v_cvt_pk_bf16_f32
    u32 lov = __builtin_bit_cast(u32, l);
    v2f lf;
    lf[0] = __builtin_bit_cast(float, lov << 16);
    lf[1] = __builtin_bit_cast(float, lov & 0xffff0000u);
    v2f r = s - lf;
    v2bf h = __builtin_convertvector(r, v2bf);
    lo = lov;
    hi = __builtin_bit_cast(u32, h);
}

#define PLO(a, b) __builtin_amdgcn_perm((a), (b), 0x05040100u)
#define PHI(a, b) __builtin_amdgcn_perm((a), (b), 0x07060302u)

// ---------------------------------------------------------------------------
// K1: dequant (unchanged from R21). L0/L1/L2 scaled by OMEGA_S; w3f f32.
// ---------------------------------------------------------------------------
__global__ __launch_bounds__(512)
void ecnr_dequant(const float* __restrict__ cent0, const int* __restrict__ lab0,
                  const float* __restrict__ cent1, const int* __restrict__ lab1,
                  const float* __restrict__ cent2, const int* __restrict__ lab2,
                  const float* __restrict__ cent3, const int* __restrict__ lab3,
                  const float* __restrict__ bias0, const float* __restrict__ bias1,
                  const float* __restrict__ bias2,
                  u16* __restrict__ wpl1, u16* __restrict__ wpl2,
                  u16* __restrict__ w0pl, float* __restrict__ w3f,
                  float* __restrict__ biasc)
{
    __shared__ u32 cpk[512];
    const int t = threadIdx.x;

    if (blockIdx.x < 512) {
        const int m = blockIdx.x >> 1, L = blockIdx.x & 1;
        if (t < 256) cpk[t] = pack2((L ? cent2 : cent1)[t] * OMEGA_S);
        __syncthreads();
        const int* lab = (L ? lab2 : lab1) + (size_t)m * 16384;
        u16* base = (L ? wpl2 : wpl1) + (size_t)m * 32768;
        #pragma unroll
        for (int i = 0; i < 4; ++i) {
            const int id = i * 512 + t;
            const int n = id & 127, c = id >> 7;
            u32 g[8];
            #pragma unroll
            for (int j = 0; j < 8; ++j) g[j] = cpk[lab[(8 * c + j) * 128 + n]];
            v4u lo, hi;
            #pragma unroll
            for (int r = 0; r < 4; ++r) {
                lo[r] = PLO(g[2 * r + 1], g[2 * r]);
                hi[r] = PHI(g[2 * r + 1], g[2 * r]);
            }
            *(v4u*)(base + c * 1024 + n * 8)         = lo;
            *(v4u*)(base + 16384 + c * 1024 + n * 8) = hi;
        }
    } else {
        const int m = blockIdx.x - 512;
        if (t < 256) cpk[t] = pack2(cent0[t] * OMEGA_S);
        __syncthreads();
        if (t < 256) {
            const int n = t & 127, c = t >> 7;
            const int* lab = lab0 + (size_t)m * 2048;
            u32 g[8];
            #pragma unroll
            for (int j = 0; j < 8; ++j) g[j] = cpk[lab[(8 * c + j) * 128 + n]];
            v4u lo, hi;
            #pragma unroll
            for (int r = 0; r < 4; ++r) {
                lo[r] = PLO(g[2 * r + 1], g[2 * r]);
                hi[r] = PHI(g[2 * r + 1], g[2 * r]);
            }
            u16* b0 = w0pl + (size_t)m * 4096;
            *(v4u*)(b0 + c * 1024 + n * 8)        = lo;
            *(v4u*)(b0 + 2048 + c * 1024 + n * 8) = hi;
        } else if (t < 384) {
            const int kk = t - 256;
            w3f[(size_t)m * 128 + kk] = cent3[lab3[(size_t)m * 128 + kk]];
        }
        if (t < 384) {
            const int li = t >> 7, kk = t & 127;
            const float* bsrc = (li == 0) ? bias0 : (li == 1) ? bias1 : bias2;
            biasc[(size_t)m * 384 + t] = bsrc[m * 128 + kk] * OMEGA_S;
        }
    }
}

// ---------------------------------------------------------------------------
// K2: fused forward — two 32-pt tiles per block, one layer out of phase.
// 256 thr = 4 waves (w = nt). LDS: 4 H planes (32x128 u16) + red = 33792 B.
// Swizzle: phys u16 off = ((off>>3) ^ (ln&15))<<3 | (off&7).
// ---------------------------------------------------------------------------

// epilogue: 16 accs -> sin -> bf16 lo+hi planes (swizzled write)
#define EPI_FULL(ACC, ROWLO, ROWHI)                               \
    do {                                                          \
        _Pragma("unroll")                                         \
        for (int gg = 0; gg < 4; ++gg) {                          \
            const int wo = (((4 * nt + gg) ^ key) << 3) + 4 * q;  \
            const float s0 = sinrev((ACC)[4 * gg + 0]);           \
            const float s1 = sinrev((ACC)[4 * gg + 1]);           \
            const float s2 = sinrev((ACC)[4 * gg + 2]);           \
            const float s3 = sinrev((ACC)[4 * gg + 3]);           \
            u32 l0, h0, l1, h1;                                   \
            pk2(s0, s1, l0, h0);                                  \
            pk2(s2, s3, l1, h1);                                  \
            v2u lov, hiv;                                         \
            lov[0] = l0; lov[1] = l1;                             \
            hiv[0] = h0; hiv[1] = h1;                             \
            *(v2u*)((ROWLO) + wo) = lov;                          \
            *(v2u*)((ROWHI) + wo) = hiv;                          \
        }                                                         \
    } while (0)

// bias init of a v16f accumulator from scaled-bias pointer BP (floats)
#define ACC_INIT(ACC, BP)                                         \
    do {                                                          \
        _Pragma("unroll")                                         \
        for (int gg = 0; gg < 4; ++gg) {                          \
            const float4 bv = *(const float4*)((BP) + 8 * gg);    \
            (ACC)[4 * gg] = bv.x; (ACC)[4 * gg + 1] = bv.y;       \
            (ACC)[4 * gg + 2] = bv.z; (ACC)[4 * gg + 3] = bv.w;   \
        }                                                         \
    } while (0)

// one layer's MFMA loop on one tile (wl8 panel must be loaded)
#define L_MFMA(ACC, WB, RLO, RHI)                                 \
    do {                                                          \
        _Pragma("unroll")                                         \
        for (int kc = 0; kc < 8; ++kc) {                          \
            const v4u whv4 = *(const v4u*)((WB) + kc * 2048 + 16384); \
            const int ro = (((2 * kc + q) ^ key) << 3);           \
            const v8bf hlo = *(const v8bf*)((RLO) + ro);          \
            const v8bf hhi = *(const v8bf*)((RHI) + ro);          \
            const v8bf wlv = __builtin_bit_cast(v8bf, wl8[kc]);   \
            const v8bf whb = __builtin_bit_cast(v8bf, whv4);      \
            (ACC) = MFMA(wlv, hlo, (ACC));                        \
            (ACC) = MFMA(wlv, hhi, (ACC));                        \
            (ACC) = MFMA(whb, hlo, (ACC));                        \
        }                                                         \
    } while (0)

// fused L3 tail: f32 dot of sin(acc) with w3 regs, q-reduce, red write
#define L3TAIL(ACC, REDOFF)                                       \
    do {                                                          \
        float p;                                                  \
        p  = wv0.x * sinrev((ACC)[0]);                            \
        p += wv0.y * sinrev((ACC)[1]);                            \
        p += wv0.z * sinrev((ACC)[2]);                            \
        p += wv0.w * sinrev((ACC)[3]);                            \
        p += wv1.x * sinrev((ACC)[4]);                            \
        p += wv1.y * sinrev((ACC)[5]);                            \
        p += wv1.z * sinrev((ACC)[6]);                            \
        p += wv1.w * sinrev((ACC)[7]);                            \
        p += wv2.x * sinrev((ACC)[8]);                            \
        p += wv2.y * sinrev((ACC)[9]);                            \
        p += wv2.z * sinrev((ACC)[10]);                           \
        p += wv2.w * sinrev((ACC)[11]);                           \
        p += wv3.x * sinrev((ACC)[12]);                           \
        p += wv3.y * sinrev((ACC)[13]);                           \
        p += wv3.z * sinrev((ACC)[14]);                           \
        p += wv3.w * sinrev((ACC)[15]);                           \
        p += __shfl_xor(p, 32);                                   \
        if (q == 0) red[(REDOFF) + nt * 32 + ln] = p;             \
    } while (0)

__global__ __launch_bounds__(256, 4)
void ecnr_fwd(const float* __restrict__ x,
              const int*   __restrict__ mlp_idx,
              const int*   __restrict__ block_idx,
              const float* __restrict__ latent,
              const float* __restrict__ bias3,
              const u16* __restrict__ wpl1, const u16* __restrict__ wpl2,
              const u16* __restrict__ w0pl, const float* __restrict__ w3f,
              const float* __restrict__ biasc,
              float* __restrict__ out)
{
    __shared__ __attribute__((aligned(16))) u16   Hbuf[4][32 * HSTRIDE];
    __shared__ __attribute__((aligned(16))) float red[256];

    // XCD swizzle (bijective): xcd=g[2:0], tile=g[7:3], sample=g[12:8]<<3|xcd
    const int g    = blockIdx.x;
    const int b    = ((g >> 8) << 3) | (g & 7);    // sample 0..255
    const int p0   = ((g >> 3) & 31) * 64;         // point base (64 points)
    const int m    = mlp_idx[b];

    const int t  = threadIdx.x;
    const int l  = t & 63, nt = t >> 6;     // wave = channel tile nt (0..3)
    const int q  = l >> 5, ln = l & 31;
    const int nn   = nt * 32 + ln;          // channel (A operand / W row)
    const int bidx = nt * 32 + 4 * q;       // bias frag base index
    const int key  = ln & 15;               // LDS swizzle key

    const float* bc = biasc + (size_t)m * 384;
    // T1 = points p0+[0,32), T2 = points p0+[32,64); lane ln owns one row each
    const float* xp = x + (size_t)(b * 2048 + p0 + ln) * 3;
    const float x10 = xp[0],  x11 = xp[1],  x12 = xp[2];    // T1
    const float x20 = xp[96], x21 = xp[97], x22 = xp[98];   // T2
    const u16* w0p = w0pl + (size_t)m * 4096 + q * 1024 + nn * 8;
    const v4u w0lo = *(const v4u*)(w0p);
    const v4u w0hi = *(const v4u*)(w0p + 2048);
    const float* zp = latent + ((size_t)m * 8 + block_idx[b]) * 13;
    float zr[8];
    #pragma unroll
    for (int j = 0; j < 8; ++j) zr[j] = zp[q * 5 + j];

    const u16* Wb1 = wpl1 + (size_t)m * 32768 + q * 1024 + nn * 8;
    const u16* Wb2 = wpl2 + (size_t)m * 32768 + q * 1024 + nn * 8;

    // per-tile H plane row bases
    u16* rl1 = Hbuf[0] + ln * HSTRIDE;
    u16* rh1 = Hbuf[1] + ln * HSTRIDE;
    u16* rl2 = Hbuf[2] + ln * HSTRIDE;
    u16* rh2 = Hbuf[3] + ln * HSTRIDE;

    v16f acc1, acc2;
    v4u  wl8[8];

    // ================= Seg0: T1.L0 (mfma+epi) + T2.L0 (mfma) =================
    {
        float fin1[8], fin2[8];
        if (q == 0) {
            fin1[0] = x10; fin1[1] = x11; fin1[2] = x12;
            fin2[0] = x20; fin2[1] = x21; fin2[2] = x22;
            #pragma unroll
            for (int j = 0; j < 5; ++j) { fin1[3 + j] = zr[j]; fin2[3 + j] = zr[j]; }
        } else {
            #pragma unroll
            for (int j = 0; j < 8; ++j) { fin1[j] = zr[j]; fin2[j] = zr[j]; }
        }
        v4u il1, ih1, il2, ih2;
        #pragma unroll
        for (int r = 0; r < 4; ++r) {
            u32 plo, phi;
            pk2(fin1[2 * r], fin1[2 * r + 1], plo, phi);
            il1[r] = plo; ih1[r] = phi;
            pk2(fin2[2 * r], fin2[2 * r + 1], plo, phi);
            il2[r] = plo; ih2[r] = phi;
        }
        const v8bf i1l = __builtin_bit_cast(v8bf, il1);
        const v8bf i1h = __builtin_bit_cast(v8bf, ih1);
        const v8bf i2l = __builtin_bit_cast(v8bf, il2);
        const v8bf i2h = __builtin_bit_cast(v8bf, ih2);
        const v8bf wl = __builtin_bit_cast(v8bf, w0lo);
        const v8bf wh = __builtin_bit_cast(v8bf, w0hi);
        ACC_INIT(acc1, bc + bidx);
        ACC_INIT(acc2, bc + bidx);
        acc1 = MFMA(wl, i1l, acc1);
        acc1 = MFMA(wl, i1h, acc1);
        acc1 = MFMA(wh, i1l, acc1);
        acc2 = MFMA(wl, i2l, acc2);
        acc2 = MFMA(wl, i2h, acc2);
        acc2 = MFMA(wh, i2l, acc2);
        EPI_FULL(acc1, rl1, rh1);
    }
    __syncthreads();  // bar1: H1 visible

    // ================= Seg1: T1.L1 mfma || T2.L0 epi =================
    {
        #pragma unroll
        for (int kc = 0; kc < 8; ++kc) wl8[kc] = *(const v4u*)(Wb1 + kc * 2048);
        ACC_INIT(acc1, bc + 128 + bidx);
        L_MFMA(acc1, Wb1, rl1, rh1);
        EPI_FULL(acc2, rl2, rh2);
    }
    __syncthreads();  // bar2: H1 reads done; H2 visible

    // ================= Seg2: T2.L1 mfma (wl8 reused) || T1.L1 epi =================
    {
        ACC_INIT(acc2, bc + 128 + bidx);
        L_MFMA(acc2, Wb1, rl2, rh2);
        EPI_FULL(acc1, rl1, rh1);
    }
    __syncthreads();  // bar3: H2 reads done; H1 visible

    // ================= Seg3: T1.L2 mfma || T2.L1 epi =================
    {
        #pragma unroll
        for (int kc = 0; kc < 8; ++kc) wl8[kc] = *(const v4u*)(Wb2 + kc * 2048);
        ACC_INIT(acc1, bc + 256 + bidx);
        L_MFMA(acc1, Wb2, rl1, rh1);
        EPI_FULL(acc2, rl2, rh2);
    }
    __syncthreads();  // bar4: H1 reads done; H2 visible

    // ============ Seg4: T2.L2 mfma (wl8 reused) || T1.L3 tail ============
    const float* w3p = w3f + (size_t)m * 128 + nt * 32 + 4 * q;
    const float4 wv0 = *(const float4*)(w3p);
    const float4 wv1 = *(const float4*)(w3p + 8);
    const float4 wv2 = *(const float4*)(w3p + 16);
    const float4 wv3 = *(const float4*)(w3p + 24);
    {
        ACC_INIT(acc2, bc + 256 + bidx);
        L_MFMA(acc2, Wb2, rl2, rh2);
        L3TAIL(acc1, 0);
    }
    // ================= Seg5: T2.L3 tail (no barrier needed before) =================
    {
        L3TAIL(acc2, 128);
    }
    __syncthreads();  // bar5: red complete

    if (t < 64) {
        const int rp = (t >> 5) * 128, rl = t & 31;
        const float o = bias3[m]
            + red[rp + rl] + red[rp + 32 + rl]
            + red[rp + 64 + rl] + red[rp + 96 + rl];
        out[(size_t)b * 2048 + p0 + t] = o;
    }
}

extern "C" void kernel_launch(void* const* d_in, const int* in_sizes, int n_in,
                              void* d_out, int out_size, void* d_ws, size_t ws_size,
                              hipStream_t stream) {
    (void)in_sizes; (void)n_in; (void)out_size; (void)ws_size;
    u16*   wpl1  = (u16*)d_ws;                          // 16 MB
    u16*   wpl2  = wpl1 + (size_t)256 * 32768;          // 16 MB
    u16*   w0pl  = wpl2 + (size_t)256 * 32768;          // 2 MB
    float* w3f   = (float*)(w0pl + (size_t)256 * 4096); // 128 KB (f32 L3 weights)
    float* biasc = w3f + (size_t)256 * 128;             // 384 KB (scaled biases)

    ecnr_dequant<<<768, 512, 0, stream>>>(
        (const float*)d_in[4],  (const int*)d_in[5],
        (const float*)d_in[7],  (const int*)d_in[8],
        (const float*)d_in[10], (const int*)d_in[11],
        (const float*)d_in[13], (const int*)d_in[14],
        (const float*)d_in[6],  (const float*)d_in[9], (const float*)d_in[12],
        wpl1, wpl2, w0pl, w3f, biasc);

    ecnr_fwd<<<8192, 256, 0, stream>>>(
        (const float*)d_in[0], (const int*)d_in[1], (const int*)d_in[2],
        (const float*)d_in[3],
        (const float*)d_in[15],
        wpl1, wpl2, w0pl, w3f, biasc,
        (float*)d_out);
}

// Round 8
// 221.928 us; speedup vs baseline: 1.0457x; 1.0457x over previous
//
#include <hip/hip_runtime.h>

// ECNR forward, R23 = R21 (verbatim) + slot-staggered block start:
//  R22 post-mortem: MFMA blocks its issuing wave on CDNA4 -> intra-wave
//  MFMA/VALU pairing is impossible; overlap must be CROSS-WAVE. Each SIMD
//  hosts 4 waves from 4 different blocks, but residents launch together and
//  run identical-length phases -> phase-locked; serial model MFMA(43.5us) +
//  VALU(48us) + slack(30us) = 121.5 ~= measured 122us across 3 schedules.
//  R23 staggers same-CU slots ((g>>8)&3) by ~0/0.8k/3.0k/3.8k cycles via
//  s_sleep so one slot's MFMA burst overlaps another's sin/pack epilogue.
//  Everything else is R21: dual-chain waves, fused-L3 f32 tail, 32KB no-pad
//  swizzled LDS, biases from global biasc. absmax 0.03320312 unchanged.

typedef unsigned int u32;
typedef unsigned short u16;
typedef __bf16 v8bf  __attribute__((ext_vector_type(8)));
typedef __bf16 v2bf  __attribute__((ext_vector_type(2)));
typedef float  v16f  __attribute__((ext_vector_type(16)));
typedef float  v2f   __attribute__((ext_vector_type(2)));
typedef u32    v4u   __attribute__((ext_vector_type(4)));
typedef u32    v2u   __attribute__((ext_vector_type(2)));

#define MFMA(a, b, c) __builtin_amdgcn_mfma_f32_32x32x16_bf16(a, b, c, 0, 0, 0)

#define HSTRIDE 128                 // u16; 256 B rows, XOR-swizzled chunks
#define OMEGA_S 4.774648292756860f  // 30/(2*pi)

// acc already in revolutions: sin = v_sin(v_fract(acc))
__device__ __forceinline__ float sinrev(float rev) {
    return __builtin_amdgcn_sinf(__builtin_amdgcn_fractf(rev));
}

__device__ __forceinline__ u32 pack2(float c) {
    __bf16 b0 = (__bf16)c;
    float  f0 = (float)b0;
    __bf16 b1 = (__bf16)(c - f0);
    return (u32)__builtin_bit_cast(u16, b0) |
           ((u32)__builtin_bit_cast(u16, b1) << 16);
}

// two floats -> packed lo (bf16x2) and packed hi (residual bf16x2), RNE
__device__ __forceinline__ void pk2(float s0, float s1, u32& lo, u32& hi) {
    v2f s; s[0] = s0; s[1] = s1;
    v2bf l = __builtin_convertvector(s, v2bf);        // v_cvt_pk_bf16_f32
    u32 lov = __builtin_bit_cast(u32, l);
    v2f lf;
    lf[0] = __builtin_bit_cast(float, lov << 16);
    lf[1] = __builtin_bit_cast(float, lov & 0xffff0000u);
    v2f r = s - lf;
    v2bf h = __builtin_convertvector(r, v2bf);
    lo = lov;
    hi = __builtin_bit_cast(u32, h);
}

#define PLO(a, b) __builtin_amdgcn_perm((a), (b), 0x05040100u)
#define PHI(a, b) __builtin_amdgcn_perm((a), (b), 0x07060302u)

// ---------------------------------------------------------------------------
// K1: dequant (unchanged). L0/L1/L2 scaled by OMEGA_S; w3f f32.
// ---------------------------------------------------------------------------
__global__ __launch_bounds__(512)
void ecnr_dequant(const float* __restrict__ cent0, const int* __restrict__ lab0,
                  const float* __restrict__ cent1, const int* __restrict__ lab1,
                  const float* __restrict__ cent2, const int* __restrict__ lab2,
                  const float* __restrict__ cent3, const int* __restrict__ lab3,
                  const float* __restrict__ bias0, const float* __restrict__ bias1,
                  const float* __restrict__ bias2,
                  u16* __restrict__ wpl1, u16* __restrict__ wpl2,
                  u16* __restrict__ w0pl, float* __restrict__ w3f,
                  float* __restrict__ biasc)
{
    __shared__ u32 cpk[512];
    const int t = threadIdx.x;

    if (blockIdx.x < 512) {
        const int m = blockIdx.x >> 1, L = blockIdx.x & 1;
        if (t < 256) cpk[t] = pack2((L ? cent2 : cent1)[t] * OMEGA_S);
        __syncthreads();
        const int* lab = (L ? lab2 : lab1) + (size_t)m * 16384;
        u16* base = (L ? wpl2 : wpl1) + (size_t)m * 32768;
        #pragma unroll
        for (int i = 0; i < 4; ++i) {
            const int id = i * 512 + t;
            const int n = id & 127, c = id >> 7;
            u32 g[8];
            #pragma unroll
            for (int j = 0; j < 8; ++j) g[j] = cpk[lab[(8 * c + j) * 128 + n]];
            v4u lo, hi;
            #pragma unroll
            for (int r = 0; r < 4; ++r) {
                lo[r] = PLO(g[2 * r + 1], g[2 * r]);
                hi[r] = PHI(g[2 * r + 1], g[2 * r]);
            }
            *(v4u*)(base + c * 1024 + n * 8)         = lo;
            *(v4u*)(base + 16384 + c * 1024 + n * 8) = hi;
        }
    } else {
        const int m = blockIdx.x - 512;
        if (t < 256) cpk[t] = pack2(cent0[t] * OMEGA_S);
        __syncthreads();
        if (t < 256) {
            const int n = t & 127, c = t >> 7;
            const int* lab = lab0 + (size_t)m * 2048;
            u32 g[8];
            #pragma unroll
            for (int j = 0; j < 8; ++j) g[j] = cpk[lab[(8 * c + j) * 128 + n]];
            v4u lo, hi;
            #pragma unroll
            for (int r = 0; r < 4; ++r) {
                lo[r] = PLO(g[2 * r + 1], g[2 * r]);
                hi[r] = PHI(g[2 * r + 1], g[2 * r]);
            }
            u16* b0 = w0pl + (size_t)m * 4096;
            *(v4u*)(b0 + c * 1024 + n * 8)        = lo;
            *(v4u*)(b0 + 2048 + c * 1024 + n * 8) = hi;
        } else if (t < 384) {
            const int kk = t - 256;
            w3f[(size_t)m * 128 + kk] = cent3[lab3[(size_t)m * 128 + kk]];
        }
        if (t < 384) {
            const int li = t >> 7, kk = t & 127;
            const float* bsrc = (li == 0) ? bias0 : (li == 1) ? bias1 : bias2;
            biasc[(size_t)m * 384 + t] = bsrc[m * 128 + kk] * OMEGA_S;
        }
    }
}

// ---------------------------------------------------------------------------
// K2: fused forward, dual-chain waves, swizzled 32KB LDS, fused-L3 tail,
// slot-staggered start. 256 thr = 4 waves (w = nt).
// Chain A = points [0,32), chain B = [32,64).
// LDS: Hlo + Hhi + red = 33792 B -> 4 blocks/CU.
// ---------------------------------------------------------------------------

// epilogue: 16 accs -> sin -> bf16 lo+hi planes (swizzled write)
#define EPI_FULL(ACC, ROWLO, ROWHI)                               \
    do {                                                          \
        _Pragma("unroll")                                         \
        for (int gg = 0; gg < 4; ++gg) {                          \
            const int wo = (((4 * nt + gg) ^ key) << 3) + 4 * q;  \
            const float s0 = sinrev((ACC)[4 * gg + 0]);           \
            const float s1 = sinrev((ACC)[4 * gg + 1]);           \
            const float s2 = sinrev((ACC)[4 * gg + 2]);           \
            const float s3 = sinrev((ACC)[4 * gg + 3]);           \
            u32 l0, h0, l1, h1;                                   \
            pk2(s0, s1, l0, h0);                                  \
            pk2(s2, s3, l1, h1);                                  \
            v2u lov, hiv;                                         \
            lov[0] = l0; lov[1] = l1;                             \
            hiv[0] = h0; hiv[1] = h1;                             \
            *(v2u*)((ROWLO) + wo) = lov;                          \
            *(v2u*)((ROWHI) + wo) = hiv;                          \
        }                                                         \
    } while (0)

__global__ __launch_bounds__(256, 4)
void ecnr_fwd(const float* __restrict__ x,
              const int*   __restrict__ mlp_idx,
              const int*   __restrict__ block_idx,
              const float* __restrict__ latent,
              const float* __restrict__ bias3,
              const u16* __restrict__ wpl1, const u16* __restrict__ wpl2,
              const u16* __restrict__ w0pl, const float* __restrict__ w3f,
              const float* __restrict__ biasc,
              float* __restrict__ out)
{
    __shared__ __attribute__((aligned(16))) u16   Hlo[64 * HSTRIDE];
    __shared__ __attribute__((aligned(16))) u16   Hhi[64 * HSTRIDE];
    __shared__ __attribute__((aligned(16))) float red[256];

    // XCD swizzle (bijective): xcd=g[2:0], tile=g[7:3], sample=g[12:8]<<3|xcd
    const int g    = blockIdx.x;

    // Desync same-CU resident blocks (slots differ in g>>8). MFMA blocks its
    // issuing wave (CDNA4), so MFMA/VALU overlap must come from OTHER waves
    // on the SIMD being at a different phase. Equal-length blocks launched
    // together phase-lock (measured: MfmaUtil+VALUBusy ~= 80%, serial).
    // Stagger covers sub-phase (~1.6k cyc) and phase (~6k cyc) scales.
    switch ((g >> 8) & 3) {
        case 1: __builtin_amdgcn_s_sleep(12); break;   // ~0.8k cyc
        case 2: __builtin_amdgcn_s_sleep(47); break;   // ~3.0k cyc
        case 3: __builtin_amdgcn_s_sleep(59); break;   // ~3.8k cyc
        default: break;
    }

    const int b    = ((g >> 8) << 3) | (g & 7);    // sample 0..255
    const int p0   = ((g >> 3) & 31) * 64;         // tile * 64
    const int m    = mlp_idx[b];

    const int t  = threadIdx.x;
    const int l  = t & 63, nt = t >> 6;     // wave = channel tile nt (0..3)
    const int q  = l >> 5, ln = l & 31;
    const int nn   = nt * 32 + ln;          // channel (A operand / W row)
    const int bidx = nt * 32 + 4 * q;       // bias frag base index
    const int key  = ln & 15;               // LDS swizzle key (rows r, r+32 share)

    const float* bc = biasc + (size_t)m * 384;
    // chain A = point row ln, chain B = point row 32+ln
    const float* xpA = x + (size_t)(b * 2048 + p0 + ln) * 3;
    const float xA0 = xpA[0], xA1 = xpA[1], xA2 = xpA[2];
    const float xB0 = xpA[96], xB1 = xpA[97], xB2 = xpA[98];
    const u16* w0p = w0pl + (size_t)m * 4096 + q * 1024 + nn * 8;
    const v4u w0lo = *(const v4u*)(w0p);
    const v4u w0hi = *(const v4u*)(w0p + 2048);
    const float* zp = latent + ((size_t)m * 8 + block_idx[b]) * 13;
    float zr[8];
    #pragma unroll
    for (int j = 0; j < 8; ++j) zr[j] = zp[q * 5 + j];

    // per-row plane bases (swizzled offsets computed per access)
    u16* rowloA = Hlo + ln * HSTRIDE;
    u16* rowhiA = Hhi + ln * HSTRIDE;
    u16* rowloB = rowloA + 32 * HSTRIDE;
    u16* rowhiB = rowhiA + 32 * HSTRIDE;

    // ---- layer 0: A = W0 (regs, scaled, shared), B = input^T x2 chains ----
    {
        float finA[8], finB[8];
        if (q == 0) {
            finA[0] = xA0; finA[1] = xA1; finA[2] = xA2;
            finB[0] = xB0; finB[1] = xB1; finB[2] = xB2;
            #pragma unroll
            for (int j = 0; j < 5; ++j) { finA[3 + j] = zr[j]; finB[3 + j] = zr[j]; }
        } else {
            #pragma unroll
            for (int j = 0; j < 8; ++j) { finA[j] = zr[j]; finB[j] = zr[j]; }
        }
        v4u ilA, ihA, ilB, ihB;
        #pragma unroll
        for (int r = 0; r < 4; ++r) {
            u32 plo, phi;
            pk2(finA[2 * r], finA[2 * r + 1], plo, phi);
            ilA[r] = plo; ihA[r] = phi;
            pk2(finB[2 * r], finB[2 * r + 1], plo, phi);
            ilB[r] = plo; ihB[r] = phi;
        }
        const v8bf inloA = __builtin_bit_cast(v8bf, ilA);
        const v8bf inhiA = __builtin_bit_cast(v8bf, ihA);
        const v8bf inloB = __builtin_bit_cast(v8bf, ilB);
        const v8bf inhiB = __builtin_bit_cast(v8bf, ihB);
        const v8bf wl = __builtin_bit_cast(v8bf, w0lo);
        const v8bf wh = __builtin_bit_cast(v8bf, w0hi);
        v16f accA0, accB0;
        #pragma unroll
        for (int gg = 0; gg < 4; ++gg) {
            const float4 bv = *(const float4*)(bc + bidx + 8 * gg);
            accA0[4 * gg] = bv.x; accA0[4 * gg + 1] = bv.y;
            accA0[4 * gg + 2] = bv.z; accA0[4 * gg + 3] = bv.w;
            accB0[4 * gg] = bv.x; accB0[4 * gg + 1] = bv.y;
            accB0[4 * gg + 2] = bv.z; accB0[4 * gg + 3] = bv.w;
        }
        __builtin_amdgcn_s_setprio(1);
        accA0 = MFMA(wl, inloA, accA0); accB0 = MFMA(wl, inloB, accB0);
        accA0 = MFMA(wl, inhiA, accA0); accB0 = MFMA(wl, inhiB, accB0);
        accA0 = MFMA(wh, inloA, accA0); accB0 = MFMA(wh, inloB, accB0);
        __builtin_amdgcn_s_setprio(0);
        EPI_FULL(accA0, rowloA, rowhiA);
        EPI_FULL(accB0, rowloB, rowhiB);
    }
    __syncthreads();  // B1: H(L0) visible

    // ---- layers 1,2: A = W (wl8 panel, loop-local), B = H^T x2 ----
    v16f accA, accB;
    #pragma unroll 1
    for (int L = 0; L < 2; ++L) {
        const u16* Wb = (L ? wpl2 : wpl1) + (size_t)m * 32768 + q * 1024 + nn * 8;
        const float* bL = bc + 128 + (L << 7) + bidx;   // b1*s / b2*s (global, L2)
        #pragma unroll
        for (int gg = 0; gg < 4; ++gg) {
            const float4 bv = *(const float4*)(bL + 8 * gg);
            accA[4 * gg] = bv.x; accA[4 * gg + 1] = bv.y;
            accA[4 * gg + 2] = bv.z; accA[4 * gg + 3] = bv.w;
            accB[4 * gg] = bv.x; accB[4 * gg + 1] = bv.y;
            accB[4 * gg + 2] = bv.z; accB[4 * gg + 3] = bv.w;
        }
        v4u wl8[8];
        #pragma unroll
        for (int kc = 0; kc < 8; ++kc)
            wl8[kc] = *(const v4u*)(Wb + kc * 2048);
        #pragma unroll
        for (int kc = 0; kc < 8; ++kc) {
            const v4u whv4 = *(const v4u*)(Wb + kc * 2048 + 16384);  // issue early
            const int ro = (((2 * kc + q) ^ key) << 3);              // swizzled chunk
            const v8bf hloA = *(const v8bf*)(rowloA + ro);
            const v8bf hhiA = *(const v8bf*)(rowhiA + ro);
            const v8bf hloB = *(const v8bf*)(rowloB + ro);
            const v8bf hhiB = *(const v8bf*)(rowhiB + ro);
            const v8bf wlv = __builtin_bit_cast(v8bf, wl8[kc]);
            const v8bf whb = __builtin_bit_cast(v8bf, whv4);
            __builtin_amdgcn_s_setprio(1);
            accA = MFMA(wlv, hloA, accA); accB = MFMA(wlv, hloB, accB);
            accA = MFMA(wlv, hhiA, accA); accB = MFMA(wlv, hhiB, accB);
            accA = MFMA(whb, hloA, accA); accB = MFMA(whb, hloB, accB);
            __builtin_amdgcn_s_setprio(0);
        }
        if (L == 0) {
            __syncthreads();  // B2: all H(L0) reads done
            EPI_FULL(accA, rowloA, rowhiA);
            EPI_FULL(accB, rowloB, rowhiB);
            __syncthreads();  // B3: H(L1) visible
        }
        // L == 1: no epilogue, no barrier — fall through to fused L3 tail.
    }

    // ---- fused L3 tail: f32 dot with w3f on this thread's 16 channels ----
    // acc reg r holds channel nt*32 + (r&3) + 8*(r>>2) + 4*q of its point row.
    {
        const float* w3p = w3f + (size_t)m * 128 + nt * 32 + 4 * q;
        const float4 wv0 = *(const float4*)(w3p);
        const float4 wv1 = *(const float4*)(w3p + 8);
        const float4 wv2 = *(const float4*)(w3p + 16);
        const float4 wv3 = *(const float4*)(w3p + 24);
        float pA, pB;
        pA  = wv0.x * sinrev(accA[0]);  pB  = wv0.x * sinrev(accB[0]);
        pA += wv0.y * sinrev(accA[1]);  pB += wv0.y * sinrev(accB[1]);
        pA += wv0.z * sinrev(accA[2]);  pB += wv0.z * sinrev(accB[2]);
        pA += wv0.w * sinrev(accA[3]);  pB += wv0.w * sinrev(accB[3]);
        pA += wv1.x * sinrev(accA[4]);  pB += wv1.x * sinrev(accB[4]);
        pA += wv1.y * sinrev(accA[5]);  pB += wv1.y * sinrev(accB[5]);
        pA += wv1.z * sinrev(accA[6]);  pB += wv1.z * sinrev(accB[6]);
        pA += wv1.w * sinrev(accA[7]);  pB += wv1.w * sinrev(accB[7]);
        pA += wv2.x * sinrev(accA[8]);  pB += wv2.x * sinrev(accB[8]);
        pA += wv2.y * sinrev(accA[9]);  pB += wv2.y * sinrev(accB[9]);
        pA += wv2.z * sinrev(accA[10]); pB += wv2.z * sinrev(accB[10]);
        pA += wv2.w * sinrev(accA[11]); pB += wv2.w * sinrev(accB[11]);
        pA += wv3.x * sinrev(accA[12]); pB += wv3.x * sinrev(accB[12]);
        pA += wv3.y * sinrev(accA[13]); pB += wv3.y * sinrev(accB[13]);
        pA += wv3.z * sinrev(accA[14]); pB += wv3.z * sinrev(accB[14]);
        pA += wv3.w * sinrev(accA[15]); pB += wv3.w * sinrev(accB[15]);
        // q-reduce: lanes ln and ln+32 hold the two channel-halves of point ln
        pA += __shfl_xor(pA, 32);
        pB += __shfl_xor(pB, 32);
        if (q == 0) {
            red[nt * 32 + ln]       = pA;
            red[128 + nt * 32 + ln] = pB;
        }
    }
    __syncthreads();  // B6

    if (t < 64) {
        const int rp = (t >> 5) * 128, rl = t & 31;
        const float o = bias3[m]
            + red[rp + rl] + red[rp + 32 + rl]
            + red[rp + 64 + rl] + red[rp + 96 + rl];
        out[(size_t)b * 2048 + p0 + t] = o;
    }
}

extern "C" void kernel_launch(void* const* d_in, const int* in_sizes, int n_in,
                              void* d_out, int out_size, void* d_ws, size_t ws_size,
                              hipStream_t stream) {
    (void)in_sizes; (void)n_in; (void)out_size; (void)ws_size;
    u16*   wpl1  = (u16*)d_ws;                          // 16 MB
    u16*   wpl2  = wpl1 + (size_t)256 * 32768;          // 16 MB
    u16*   w0pl  = wpl2 + (size_t)256 * 32768;          // 2 MB
    float* w3f   = (float*)(w0pl + (size_t)256 * 4096); // 128 KB (f32 L3 weights)
    float* biasc = w3f + (size_t)256 * 128;             // 384 KB (scaled biases)

    ecnr_dequant<<<768, 512, 0, stream>>>(
        (const float*)d_in[4],  (const int*)d_in[5],
        (const float*)d_in[7],  (const int*)d_in[8],
        (const float*)d_in[10], (const int*)d_in[11],
        (const float*)d_in[13], (const int*)d_in[14],
        (const float*)d_in[6],  (const float*)d_in[9], (const float*)d_in[12],
        wpl1, wpl2, w0pl, w3f, biasc);

    ecnr_fwd<<<8192, 256, 0, stream>>>(
        (const float*)d_in[0], (const int*)d_in[1], (const int*)d_in[2],
        (const float*)d_in[3],
        (const float*)d_in[15],
        wpl1, wpl2, w0pl, w3f, biasc,
        (float*)d_out);
}